// Round 5
// baseline (437.726 us; speedup 1.0000x reference)
//
#include <hip/hip_runtime.h>

// GCN, bf16 intermediate (harness tolerance is bf16-grade):
//   pass A: bin edges by dst-range into stripe-private (XCD-local) bins
//   pass B: per-range CSR build (all stores in an L2-resident 31KB window)
//   3x (X@W -> bf16 Hs premul dinv -> pull-aggregate float4-gather) -> pool -> MLP
constexpr int N = 100000;
constexpr int E = 1250000;
constexpr int G = 64;
constexpr int K = 40;          // bucket capacity; Poisson(12.5) tail ~1e-9
constexpr int NB = 512;        // dst ranges
constexpr int RANGE = 196;     // nodes per range (196*512 >= N)
constexpr int CAP = 512;       // per (stripe,range) bin capacity (~lambda+12sigma)
constexpr int NSTRIPE = 8;     // ~XCDs
constexpr int OVF_CAP = 65536; // exact-overflow list capacity (expected use: 0)

__device__ inline unsigned bf16pack(float a, float b) {  // RNE, low=a high=b
  unsigned ua = __float_as_uint(a);
  ua = (ua + 0x7FFF + ((ua >> 16) & 1)) >> 16;
  unsigned ub = __float_as_uint(b);
  ub = (ub + 0x7FFF + ((ub >> 16) & 1)) & 0xFFFF0000u;
  return ua | ub;
}

// ---- pass A: bin (src,dst) by dst/RANGE, stripe-private --------------------
__global__ void bin_kernel(const int* __restrict__ src, const int* __restrict__ dst,
                           uint2* __restrict__ bins, int* __restrict__ bin_cnt,
                           int* __restrict__ cnt, int* __restrict__ ovf,
                           int* __restrict__ ovf_cnt) {
  int e = blockIdx.x * blockDim.x + threadIdx.x;
  if (e >= E) return;
  int d = dst[e], s = src[e];
  int b = d / RANGE;
  int stripe = blockIdx.x & (NSTRIPE - 1);
  int bi = stripe * NB + b;
  int p = atomicAdd(&bin_cnt[bi], 1);
  if (p < CAP) {
    bins[(size_t)bi * CAP + p] = make_uint2((unsigned)s, (unsigned)d);
  } else {                    // exact fallback: count degree here, spill edge
    atomicAdd(&cnt[d], 1);
    int q = atomicAdd(ovf_cnt, 1);
    if (q < OVF_CAP) { ovf[2 * q] = s; ovf[2 * q + 1] = d; }
  }
}

// ---- pass B: per-range CSR fill (one block per 196-node range) -------------
__global__ void fill_kernel(const uint2* __restrict__ bins, const int* __restrict__ bin_cnt,
                            int* __restrict__ cnt, int* __restrict__ csr,
                            int* __restrict__ ovf, int* __restrict__ ovf_cnt) {
  int b = blockIdx.x;
  for (int stripe = 0; stripe < NSTRIPE; stripe++) {
    int bi = stripe * NB + b;
    int m = min(bin_cnt[bi], CAP);
    const uint2* seg = bins + (size_t)bi * CAP;
    for (int i = threadIdx.x; i < m; i += blockDim.x) {
      uint2 ed = seg[i];
      int d = (int)ed.y;
      int slot = atomicAdd(&cnt[d], 1);
      if (slot < K) {
        csr[d * K + slot] = (int)ed.x;
      } else {
        int q = atomicAdd(ovf_cnt, 1);
        if (q < OVF_CAP) { ovf[2 * q] = (int)ed.x; ovf[2 * q + 1] = d; }
      }
    }
  }
}

// ---- Hs(bf16) = (X @ W) * dinv[row], 32 rows/block -------------------------
constexpr int XS_STRIDE = 68;
__global__ void gemm_premul_kernel(const float* __restrict__ X, const float* __restrict__ W,
                                   const int* __restrict__ cnt, unsigned* __restrict__ Hs2) {
  __shared__ float Ws[64 * 64];
  __shared__ float Xs[32 * XS_STRIDE];
  int tid = threadIdx.x;
  const float4* W4 = (const float4*)W;
#pragma unroll
  for (int j = 0; j < 4; j++)
    ((float4*)Ws)[tid + j * 256] = W4[tid + j * 256];
  int row0 = blockIdx.x * 32;
  const float4* X4 = (const float4*)(X + row0 * 64);
#pragma unroll
  for (int j = 0; j < 2; j++) {
    int idx = tid + j * 256;
    int r = idx >> 4, q = idx & 15;
    *((float4*)&Xs[r * XS_STRIDE + q * 4]) = X4[idx];
  }
  __syncthreads();
  int r0 = tid >> 4;
  int c = (tid & 15) * 4;
  float4 acc0 = {0, 0, 0, 0}, acc1 = {0, 0, 0, 0};
#pragma unroll
  for (int k = 0; k < 64; k++) {
    float4 w = *((const float4*)&Ws[k * 64 + c]);
    float xa = Xs[r0 * XS_STRIDE + k];
    float xb = Xs[(r0 + 16) * XS_STRIDE + k];
    acc0.x += xa * w.x; acc0.y += xa * w.y; acc0.z += xa * w.z; acc0.w += xa * w.w;
    acc1.x += xb * w.x; acc1.y += xb * w.y; acc1.z += xb * w.z; acc1.w += xb * w.w;
  }
  int ra = row0 + r0, rb = ra + 16;
  float da = rsqrtf((float)cnt[ra] + 1.0f);
  float db = rsqrtf((float)cnt[rb] + 1.0f);
  uint2 pa = make_uint2(bf16pack(acc0.x * da, acc0.y * da), bf16pack(acc0.z * da, acc0.w * da));
  uint2 pb = make_uint2(bf16pack(acc1.x * db, acc1.y * db), bf16pack(acc1.z * db, acc1.w * db));
  ((uint2*)Hs2)[ra * 16 + (tid & 15)] = pa;
  ((uint2*)Hs2)[rb * 16 + (tid & 15)] = pb;
}

// ---- pull aggregation: one wave/node, 4 edges in flight, bf16 rows ---------
__global__ void agg_kernel(const unsigned* __restrict__ Hs2, const int* __restrict__ cnt,
                           const int* __restrict__ csr, const int* __restrict__ ovf,
                           const int* __restrict__ ovf_cnt, const float* __restrict__ b,
                           float* __restrict__ Xout) {
  int node = (blockIdx.x * blockDim.x + threadIdx.x) >> 6;
  int lane = threadIdx.x & 63;
  if (node >= N) return;
  int g = lane >> 4;
  int i = lane & 15;
  int c = cnt[node];
  int m = min(c, K);
  int sv = (lane < m) ? csr[node * K + lane] : node;
  const uint2* H2 = (const uint2*)Hs2;
  float4 acc = {0, 0, 0, 0};
  for (int k = 0; k < m; k += 4) {
    int j = k + g;
    int s = __shfl(sv, j);
    bool valid = j < m;
    uint2 h = H2[(valid ? s : node) * 16 + i];
    if (valid) {
      acc.x += __uint_as_float(h.x << 16);
      acc.y += __uint_as_float(h.x & 0xFFFF0000u);
      acc.z += __uint_as_float(h.y << 16);
      acc.w += __uint_as_float(h.y & 0xFFFF0000u);
    }
  }
  int on = min(*ovf_cnt, OVF_CAP);
  if (on > 0 && g == 0) {
    for (int j = 0; j < on; j++)
      if (ovf[2 * j + 1] == node) {
        uint2 h = H2[ovf[2 * j] * 16 + i];
        acc.x += __uint_as_float(h.x << 16);
        acc.y += __uint_as_float(h.x & 0xFFFF0000u);
        acc.z += __uint_as_float(h.y << 16);
        acc.w += __uint_as_float(h.y & 0xFFFF0000u);
      }
  }
#pragma unroll
  for (int off = 16; off < 64; off <<= 1) {
    acc.x += __shfl_xor(acc.x, off);
    acc.y += __shfl_xor(acc.y, off);
    acc.z += __shfl_xor(acc.z, off);
    acc.w += __shfl_xor(acc.w, off);
  }
  if (g == 0) {
    uint2 hs = H2[node * 16 + i];
    float4 bb = ((const float4*)b)[i];
    float di = rsqrtf((float)c + 1.0f);
    float4 o;
    o.x = fmaxf(di * (acc.x + __uint_as_float(hs.x << 16)) + bb.x, 0.f);
    o.y = fmaxf(di * (acc.y + __uint_as_float(hs.x & 0xFFFF0000u)) + bb.y, 0.f);
    o.z = fmaxf(di * (acc.z + __uint_as_float(hs.y << 16)) + bb.z, 0.f);
    o.w = fmaxf(di * (acc.w + __uint_as_float(hs.y & 0xFFFF0000u)) + bb.w, 0.f);
    ((float4*)Xout)[node * 16 + i] = o;
  }
}

// ---- pool + classifier -----------------------------------------------------
__global__ void pool_kernel(const float* __restrict__ X, const int* __restrict__ batch,
                            float* __restrict__ sums, float* __restrict__ cnts) {
  int lane = threadIdx.x & 63;
  int wid = (blockIdx.x * blockDim.x + threadIdx.x) >> 6;
  int nw = (gridDim.x * blockDim.x) >> 6;
  int per = (N + nw - 1) / nw;
  int start = wid * per;
  int end = min(start + per, N);
  float acc = 0.f, cnt = 0.f;
  int cur = -1;
  for (int n = start; n < end; n++) {
    int g = batch[n];
    if (g != cur) {
      if (cur >= 0) {
        atomicAdd(&sums[cur * 64 + lane], acc);
        if (lane == 0) atomicAdd(&cnts[cur], cnt);
      }
      cur = g; acc = 0.f; cnt = 0.f;
    }
    acc += X[n * 64 + lane];
    cnt += 1.f;
  }
  if (cur >= 0) {
    atomicAdd(&sums[cur * 64 + lane], acc);
    if (lane == 0) atomicAdd(&cnts[cur], cnt);
  }
}

__global__ void classifier_kernel(const float* __restrict__ sums, const float* __restrict__ cnts,
                                  const float* __restrict__ Wc1, const float* __restrict__ bc1,
                                  const float* __restrict__ Wc2, const float* __restrict__ bc2,
                                  float* __restrict__ out) {
  __shared__ float pooled[64 * 64];
  __shared__ float z[64 * 32];
  int tid = threadIdx.x;
  for (int idx = tid; idx < 64 * 64; idx += 256) {
    int g = idx >> 6;
    pooled[idx] = sums[idx] / fmaxf(cnts[g], 1.0f);
  }
  __syncthreads();
  for (int idx = tid; idx < 64 * 32; idx += 256) {
    int g = idx >> 5, j = idx & 31;
    float acc = bc1[j];
#pragma unroll
    for (int c = 0; c < 64; c++) acc += pooled[g * 64 + c] * Wc1[c * 32 + j];
    z[idx] = fmaxf(acc, 0.f);
  }
  __syncthreads();
  for (int idx = tid; idx < 128; idx += 256) {
    int g = idx >> 1, k = idx & 1;
    float acc = bc2[k];
#pragma unroll
    for (int j = 0; j < 32; j++) acc += z[g * 32 + j] * Wc2[j * 2 + k];
    out[idx] = acc;
  }
}

// ---- launch ----------------------------------------------------------------
extern "C" void kernel_launch(void* const* d_in, const int* in_sizes, int n_in,
                              void* d_out, int out_size, void* d_ws, size_t ws_size,
                              hipStream_t stream) {
  const float* x   = (const float*)d_in[0];
  const float* W1  = (const float*)d_in[1];
  const float* b1  = (const float*)d_in[2];
  const float* W2  = (const float*)d_in[3];
  const float* b2  = (const float*)d_in[4];
  const float* W3  = (const float*)d_in[5];
  const float* b3  = (const float*)d_in[6];
  const float* Wc1 = (const float*)d_in[7];
  const float* bc1 = (const float*)d_in[8];
  const float* Wc2 = (const float*)d_in[9];
  const float* bc2 = (const float*)d_in[10];
  const int* ei    = (const int*)d_in[11];
  const int* batch = (const int*)d_in[12];
  const int* src  = ei;
  const int* dstp = ei + E;

  char* ws = (char*)d_ws;
  size_t off = 0;
  auto alloc = [&](size_t bytes) {
    char* p = ws + off;
    off += (bytes + 255) & ~size_t(255);
    return p;
  };
  int*      cnt     = (int*)alloc((size_t)(N + 1) * 4);
  int*      bin_cnt = (int*)alloc((size_t)NSTRIPE * NB * 4);
  uint2*    bins    = (uint2*)alloc((size_t)NSTRIPE * NB * CAP * 8);   // 16 MB
  int*      csr     = (int*)alloc((size_t)N * K * 4);                  // 16 MB
  int*      ovf     = (int*)alloc((size_t)OVF_CAP * 2 * 4);
  unsigned* Hs      = (unsigned*)alloc((size_t)N * 64 * 2);            // bf16
  float*    B1      = (float*)alloc((size_t)N * 64 * 4);
  float*    sums    = (float*)alloc((size_t)(G * 64 + G) * 4);
  float*    cnts    = sums + G * 64;
  int*      ovf_cnt = cnt + N;

  hipMemsetAsync(cnt, 0, (size_t)(N + 1) * 4, stream);
  hipMemsetAsync(bin_cnt, 0, (size_t)NSTRIPE * NB * 4, stream);
  hipMemsetAsync(sums, 0, (size_t)(G * 64 + G) * 4, stream);

  bin_kernel<<<(E + 255) / 256, 256, 0, stream>>>(src, dstp, bins, bin_cnt, cnt, ovf, ovf_cnt);
  fill_kernel<<<NB, 256, 0, stream>>>(bins, bin_cnt, cnt, csr, ovf, ovf_cnt);

  const float* Xc = x;
  const float* Wl[3] = {W1, W2, W3};
  const float* bl[3] = {b1, b2, b3};
  for (int l = 0; l < 3; l++) {
    gemm_premul_kernel<<<N / 32 + 1, 256, 0, stream>>>(Xc, Wl[l], cnt, Hs);
    agg_kernel<<<(N * 64 + 255) / 256, 256, 0, stream>>>(Hs, cnt, csr, ovf, ovf_cnt, bl[l], B1);
    Xc = B1;
  }

  pool_kernel<<<512, 256, 0, stream>>>(Xc, batch, sums, cnts);
  classifier_kernel<<<1, 256, 0, stream>>>(sums, cnts, Wc1, bc1, Wc2, bc2, (float*)d_out);
}

// Round 6
// 392.595 us; speedup vs baseline: 1.1150x; 1.1150x over previous
//
#include <hip/hip_runtime.h>

// GCN, bf16 Hs intermediate:
//   single-pass bucket CSR (K=32 -> 2 aligned lines/node, exact overflow list)
//   3x (X@W premul dinv -> bf16; pull-aggregate uint4 gathers, 8 edges in flight)
//   mean-pool -> classifier MLP
constexpr int N = 100000;
constexpr int E = 1250000;
constexpr int G = 64;
constexpr int K = 32;           // bucket cap; Poisson(12.5) P(>32)*N ~ 0.1, exact ovf path
constexpr int OVF_CAP = 65536;

__device__ inline unsigned bf16pack(float a, float b) {  // RNE, low=a high=b
  unsigned ua = __float_as_uint(a);
  ua = (ua + 0x7FFF + ((ua >> 16) & 1)) >> 16;
  unsigned ub = __float_as_uint(b);
  ub = (ub + 0x7FFF + ((ub >> 16) & 1)) & 0xFFFF0000u;
  return ua | ub;
}

// ---- graph build: one pass, slot = atomicAdd, store src ---------------------
__global__ void build_kernel(const int* __restrict__ src, const int* __restrict__ dst,
                             int* __restrict__ cnt, int* __restrict__ csr,
                             int* __restrict__ ovf, int* __restrict__ ovf_cnt) {
  int e = blockIdx.x * blockDim.x + threadIdx.x;
  if (e >= E) return;
  int d = dst[e], s = src[e];
  int slot = atomicAdd(&cnt[d], 1);
  if (slot < K) {
    csr[d * K + slot] = s;
  } else {
    int q = atomicAdd(ovf_cnt, 1);
    if (q < OVF_CAP) { ovf[2 * q] = s; ovf[2 * q + 1] = d; }
  }
}

// ---- Hs(bf16) = (X @ W) * dinv[row], 32 rows/block, grid = N/32 exactly -----
constexpr int XS_STRIDE = 68;
__global__ void gemm_premul_kernel(const float* __restrict__ X, const float* __restrict__ W,
                                   const int* __restrict__ cnt, unsigned* __restrict__ Hs2) {
  __shared__ float Ws[64 * 64];
  __shared__ float Xs[32 * XS_STRIDE];
  int tid = threadIdx.x;
  const float4* W4 = (const float4*)W;
#pragma unroll
  for (int j = 0; j < 4; j++)
    ((float4*)Ws)[tid + j * 256] = W4[tid + j * 256];
  int row0 = blockIdx.x * 32;
  const float4* X4 = (const float4*)(X + row0 * 64);
#pragma unroll
  for (int j = 0; j < 2; j++) {
    int idx = tid + j * 256;
    int r = idx >> 4, q = idx & 15;
    *((float4*)&Xs[r * XS_STRIDE + q * 4]) = X4[idx];
  }
  __syncthreads();
  int r0 = tid >> 4;
  int c = (tid & 15) * 4;
  float4 acc0 = {0, 0, 0, 0}, acc1 = {0, 0, 0, 0};
#pragma unroll
  for (int k = 0; k < 64; k++) {
    float4 w = *((const float4*)&Ws[k * 64 + c]);
    float xa = Xs[r0 * XS_STRIDE + k];
    float xb = Xs[(r0 + 16) * XS_STRIDE + k];
    acc0.x += xa * w.x; acc0.y += xa * w.y; acc0.z += xa * w.z; acc0.w += xa * w.w;
    acc1.x += xb * w.x; acc1.y += xb * w.y; acc1.z += xb * w.z; acc1.w += xb * w.w;
  }
  int ra = row0 + r0, rb = ra + 16;
  float da = rsqrtf((float)cnt[ra] + 1.0f);
  float db = rsqrtf((float)cnt[rb] + 1.0f);
  uint2 pa = make_uint2(bf16pack(acc0.x * da, acc0.y * da), bf16pack(acc0.z * da, acc0.w * da));
  uint2 pb = make_uint2(bf16pack(acc1.x * db, acc1.y * db), bf16pack(acc1.z * db, acc1.w * db));
  ((uint2*)Hs2)[ra * 16 + (tid & 15)] = pa;
  ((uint2*)Hs2)[rb * 16 + (tid & 15)] = pb;
}

// ---- pull aggregation: one wave/node, uint4 gathers, 8 edges in flight -----
// lane = 8*group + i ; group g handles edge k+g, lane covers channels 8i..8i+7
__global__ void agg_kernel(const unsigned* __restrict__ Hs2, const int* __restrict__ cnt,
                           const int* __restrict__ csr, const int* __restrict__ ovf,
                           const int* __restrict__ ovf_cnt, const float* __restrict__ b,
                           float* __restrict__ Xout) {
  int node = (blockIdx.x * blockDim.x + threadIdx.x) >> 6;
  int lane = threadIdx.x & 63;
  if (node >= N) return;
  int g = lane >> 3;
  int i = lane & 7;
  int c = cnt[node];
  int m = min(c, K);
  int sv = (lane < m) ? csr[node * K + lane] : node;   // coalesced 128B bucket read
  const uint4* H4 = (const uint4*)Hs2;
  float acc0 = 0, acc1 = 0, acc2 = 0, acc3 = 0, acc4 = 0, acc5 = 0, acc6 = 0, acc7 = 0;
  for (int k = 0; k < m; k += 8) {
    int j = k + g;
    int s = __shfl(sv, j);
    bool valid = j < m;
    uint4 h = H4[(valid ? s : node) * 8 + i];
    if (valid) {
      acc0 += __uint_as_float(h.x << 16); acc1 += __uint_as_float(h.x & 0xFFFF0000u);
      acc2 += __uint_as_float(h.y << 16); acc3 += __uint_as_float(h.y & 0xFFFF0000u);
      acc4 += __uint_as_float(h.z << 16); acc5 += __uint_as_float(h.z & 0xFFFF0000u);
      acc6 += __uint_as_float(h.w << 16); acc7 += __uint_as_float(h.w & 0xFFFF0000u);
    }
  }
  int on = min(*ovf_cnt, OVF_CAP);
  if (on > 0 && g == 0) {                  // exact rare path (deg > K)
    for (int j = 0; j < on; j++)
      if (ovf[2 * j + 1] == node) {
        uint4 h = H4[ovf[2 * j] * 8 + i];
        acc0 += __uint_as_float(h.x << 16); acc1 += __uint_as_float(h.x & 0xFFFF0000u);
        acc2 += __uint_as_float(h.y << 16); acc3 += __uint_as_float(h.y & 0xFFFF0000u);
        acc4 += __uint_as_float(h.z << 16); acc5 += __uint_as_float(h.z & 0xFFFF0000u);
        acc6 += __uint_as_float(h.w << 16); acc7 += __uint_as_float(h.w & 0xFFFF0000u);
      }
  }
#pragma unroll
  for (int off = 8; off < 64; off <<= 1) {
    acc0 += __shfl_xor(acc0, off); acc1 += __shfl_xor(acc1, off);
    acc2 += __shfl_xor(acc2, off); acc3 += __shfl_xor(acc3, off);
    acc4 += __shfl_xor(acc4, off); acc5 += __shfl_xor(acc5, off);
    acc6 += __shfl_xor(acc6, off); acc7 += __shfl_xor(acc7, off);
  }
  if (g == 0) {
    uint4 hs = H4[node * 8 + i];
    float di = rsqrtf((float)c + 1.0f);
    const float4* b4 = (const float4*)b;
    float4 blo = b4[2 * i], bhi = b4[2 * i + 1];
    float4 o0, o1;
    o0.x = fmaxf(di * (acc0 + __uint_as_float(hs.x << 16)) + blo.x, 0.f);
    o0.y = fmaxf(di * (acc1 + __uint_as_float(hs.x & 0xFFFF0000u)) + blo.y, 0.f);
    o0.z = fmaxf(di * (acc2 + __uint_as_float(hs.y << 16)) + blo.z, 0.f);
    o0.w = fmaxf(di * (acc3 + __uint_as_float(hs.y & 0xFFFF0000u)) + blo.w, 0.f);
    o1.x = fmaxf(di * (acc4 + __uint_as_float(hs.z << 16)) + bhi.x, 0.f);
    o1.y = fmaxf(di * (acc5 + __uint_as_float(hs.z & 0xFFFF0000u)) + bhi.y, 0.f);
    o1.z = fmaxf(di * (acc6 + __uint_as_float(hs.w << 16)) + bhi.z, 0.f);
    o1.w = fmaxf(di * (acc7 + __uint_as_float(hs.w & 0xFFFF0000u)) + bhi.w, 0.f);
    ((float4*)Xout)[node * 16 + 2 * i] = o0;
    ((float4*)Xout)[node * 16 + 2 * i + 1] = o1;
  }
}

// ---- pool + classifier -----------------------------------------------------
__global__ void pool_kernel(const float* __restrict__ X, const int* __restrict__ batch,
                            float* __restrict__ sums, float* __restrict__ cnts) {
  int lane = threadIdx.x & 63;
  int wid = (blockIdx.x * blockDim.x + threadIdx.x) >> 6;
  int nw = (gridDim.x * blockDim.x) >> 6;
  int per = (N + nw - 1) / nw;
  int start = wid * per;
  int end = min(start + per, N);
  float acc = 0.f, cnt = 0.f;
  int cur = -1;
  for (int n = start; n < end; n++) {
    int g = batch[n];
    if (g != cur) {
      if (cur >= 0) {
        atomicAdd(&sums[cur * 64 + lane], acc);
        if (lane == 0) atomicAdd(&cnts[cur], cnt);
      }
      cur = g; acc = 0.f; cnt = 0.f;
    }
    acc += X[n * 64 + lane];
    cnt += 1.f;
  }
  if (cur >= 0) {
    atomicAdd(&sums[cur * 64 + lane], acc);
    if (lane == 0) atomicAdd(&cnts[cur], cnt);
  }
}

__global__ void classifier_kernel(const float* __restrict__ sums, const float* __restrict__ cnts,
                                  const float* __restrict__ Wc1, const float* __restrict__ bc1,
                                  const float* __restrict__ Wc2, const float* __restrict__ bc2,
                                  float* __restrict__ out) {
  __shared__ float pooled[64 * 64];
  __shared__ float z[64 * 32];
  int tid = threadIdx.x;
  for (int idx = tid; idx < 64 * 64; idx += 256) {
    int g = idx >> 6;
    pooled[idx] = sums[idx] / fmaxf(cnts[g], 1.0f);
  }
  __syncthreads();
  for (int idx = tid; idx < 64 * 32; idx += 256) {
    int g = idx >> 5, j = idx & 31;
    float acc = bc1[j];
#pragma unroll
    for (int c = 0; c < 64; c++) acc += pooled[g * 64 + c] * Wc1[c * 32 + j];
    z[idx] = fmaxf(acc, 0.f);
  }
  __syncthreads();
  for (int idx = tid; idx < 128; idx += 256) {
    int g = idx >> 1, k = idx & 1;
    float acc = bc2[k];
#pragma unroll
    for (int j = 0; j < 32; j++) acc += z[g * 32 + j] * Wc2[j * 2 + k];
    out[idx] = acc;
  }
}

// ---- launch ----------------------------------------------------------------
extern "C" void kernel_launch(void* const* d_in, const int* in_sizes, int n_in,
                              void* d_out, int out_size, void* d_ws, size_t ws_size,
                              hipStream_t stream) {
  const float* x   = (const float*)d_in[0];
  const float* W1  = (const float*)d_in[1];
  const float* b1  = (const float*)d_in[2];
  const float* W2  = (const float*)d_in[3];
  const float* b2  = (const float*)d_in[4];
  const float* W3  = (const float*)d_in[5];
  const float* b3  = (const float*)d_in[6];
  const float* Wc1 = (const float*)d_in[7];
  const float* bc1 = (const float*)d_in[8];
  const float* Wc2 = (const float*)d_in[9];
  const float* bc2 = (const float*)d_in[10];
  const int* ei    = (const int*)d_in[11];
  const int* batch = (const int*)d_in[12];
  const int* src  = ei;
  const int* dstp = ei + E;

  char* ws = (char*)d_ws;
  size_t off = 0;
  auto alloc = [&](size_t bytes) {
    char* p = ws + off;
    off += (bytes + 255) & ~size_t(255);
    return p;
  };
  int*      cnt  = (int*)alloc((size_t)(N + 1) * 4);
  int*      csr  = (int*)alloc((size_t)N * K * 4);          // 12.8 MB
  int*      ovf  = (int*)alloc((size_t)OVF_CAP * 2 * 4);
  unsigned* Hs   = (unsigned*)alloc((size_t)N * 64 * 2);    // bf16
  float*    B1   = (float*)alloc((size_t)N * 64 * 4);
  float*    sums = (float*)alloc((size_t)(G * 64 + G) * 4);
  float*    cnts = sums + G * 64;
  int*      ovf_cnt = cnt + N;

  hipMemsetAsync(cnt, 0, (size_t)(N + 1) * 4, stream);
  hipMemsetAsync(sums, 0, (size_t)(G * 64 + G) * 4, stream);

  build_kernel<<<(E + 255) / 256, 256, 0, stream>>>(src, dstp, cnt, csr, ovf, ovf_cnt);

  const float* Xc = x;
  const float* Wl[3] = {W1, W2, W3};
  const float* bl[3] = {b1, b2, b3};
  for (int l = 0; l < 3; l++) {
    gemm_premul_kernel<<<N / 32, 256, 0, stream>>>(Xc, Wl[l], cnt, Hs);  // N%32==0
    agg_kernel<<<(N * 64 + 255) / 256, 256, 0, stream>>>(Hs, cnt, csr, ovf, ovf_cnt, bl[l], B1);
    Xc = B1;
  }

  pool_kernel<<<512, 256, 0, stream>>>(Xc, batch, sums, cnts);
  classifier_kernel<<<1, 256, 0, stream>>>(sums, cnts, Wc1, bc1, Wc2, bc2, (float*)d_out);
}

// Round 7
// 359.158 us; speedup vs baseline: 1.2188x; 1.0931x over previous
//
#include <hip/hip_runtime.h>

// GCN, bf16 Hs intermediate.
// Build: XCD-striped bucket CSR — stripe = blockIdx&7 (round-robin XCD
// heuristic); each block scans an edge chunk and keeps only dst in its
// stripe's 12500-node window, so cnt/csr RMW+stores stay L2-resident.
// Then 3x (X@W premul dinv -> bf16; pull-aggregate uint4 gathers) -> pool -> MLP.
constexpr int N = 100000;
constexpr int E = 1250000;
constexpr int G = 64;
constexpr int K = 32;            // bucket cap; P(deg>32)*N ~ 0.1, exact ovf path
constexpr int OVF_CAP = 65536;
constexpr int STRIPES = 8;
constexpr int NPS = N / STRIPES;             // 12500 nodes per stripe
constexpr int CHUNK = 10240;                 // edges per block (int4-aligned)
constexpr int CPB = (E + CHUNK - 1) / CHUNK; // 123 chunks

__device__ inline unsigned bf16pack(float a, float b) {  // RNE, low=a high=b
  unsigned ua = __float_as_uint(a);
  ua = (ua + 0x7FFF + ((ua >> 16) & 1)) >> 16;
  unsigned ub = __float_as_uint(b);
  ub = (ub + 0x7FFF + ((ub >> 16) & 1)) & 0xFFFF0000u;
  return ua | ub;
}

// ---- XCD-striped build -----------------------------------------------------
__global__ void build_kernel(const int* __restrict__ src, const int* __restrict__ dst,
                             int* __restrict__ cnt, int* __restrict__ csr,
                             int* __restrict__ ovf, int* __restrict__ ovf_cnt) {
  int stripe = blockIdx.x & (STRIPES - 1);
  int chunk = blockIdx.x >> 3;
  int lo = stripe * NPS, hi = lo + NPS;
  int base = chunk * CHUNK + threadIdx.x * 4;
  auto process = [&](int s, int d) {
    if (d >= lo && d < hi) {
      int slot = atomicAdd(&cnt[d], 1);
      if (slot < K) {
        csr[d * K + slot] = s;
      } else {
        int q = atomicAdd(ovf_cnt, 1);
        if (q < OVF_CAP) { ovf[2 * q] = s; ovf[2 * q + 1] = d; }
      }
    }
  };
#pragma unroll 1
  for (int it = 0; it < CHUNK / 1024; it++, base += 1024) {
    if (base + 3 < E) {
      int4 s4 = *(const int4*)(src + base);
      int4 d4 = *(const int4*)(dst + base);
      process(s4.x, d4.x); process(s4.y, d4.y);
      process(s4.z, d4.z); process(s4.w, d4.w);
    } else {
      for (int j = 0; j < 4; j++)
        if (base + j < E) process(src[base + j], dst[base + j]);
    }
  }
}

// ---- Hs(bf16) = (X @ W) * dinv[row], 32 rows/block -------------------------
constexpr int XS_STRIDE = 68;
__global__ void gemm_premul_kernel(const float* __restrict__ X, const float* __restrict__ W,
                                   const int* __restrict__ cnt, unsigned* __restrict__ Hs2) {
  __shared__ float Ws[64 * 64];
  __shared__ float Xs[32 * XS_STRIDE];
  int tid = threadIdx.x;
  const float4* W4 = (const float4*)W;
#pragma unroll
  for (int j = 0; j < 4; j++)
    ((float4*)Ws)[tid + j * 256] = W4[tid + j * 256];
  int row0 = blockIdx.x * 32;
  const float4* X4 = (const float4*)(X + row0 * 64);
#pragma unroll
  for (int j = 0; j < 2; j++) {
    int idx = tid + j * 256;
    int r = idx >> 4, q = idx & 15;
    *((float4*)&Xs[r * XS_STRIDE + q * 4]) = X4[idx];
  }
  __syncthreads();
  int r0 = tid >> 4;
  int c = (tid & 15) * 4;
  float4 acc0 = {0, 0, 0, 0}, acc1 = {0, 0, 0, 0};
#pragma unroll
  for (int k = 0; k < 64; k++) {
    float4 w = *((const float4*)&Ws[k * 64 + c]);
    float xa = Xs[r0 * XS_STRIDE + k];
    float xb = Xs[(r0 + 16) * XS_STRIDE + k];
    acc0.x += xa * w.x; acc0.y += xa * w.y; acc0.z += xa * w.z; acc0.w += xa * w.w;
    acc1.x += xb * w.x; acc1.y += xb * w.y; acc1.z += xb * w.z; acc1.w += xb * w.w;
  }
  int ra = row0 + r0, rb = ra + 16;
  float da = rsqrtf((float)cnt[ra] + 1.0f);
  float db = rsqrtf((float)cnt[rb] + 1.0f);
  uint2 pa = make_uint2(bf16pack(acc0.x * da, acc0.y * da), bf16pack(acc0.z * da, acc0.w * da));
  uint2 pb = make_uint2(bf16pack(acc1.x * db, acc1.y * db), bf16pack(acc1.z * db, acc1.w * db));
  ((uint2*)Hs2)[ra * 16 + (tid & 15)] = pa;
  ((uint2*)Hs2)[rb * 16 + (tid & 15)] = pb;
}

// ---- pull aggregation: one wave/node, uint4 gathers, 8 edges in flight -----
// Node mapping striped like build so csr/cnt reads hit the writing XCD's L2.
__global__ void agg_kernel(const unsigned* __restrict__ Hs2, const int* __restrict__ cnt,
                           const int* __restrict__ csr, const int* __restrict__ ovf,
                           const int* __restrict__ ovf_cnt, const float* __restrict__ b,
                           float* __restrict__ Xout) {
  int stripe = blockIdx.x & (STRIPES - 1);
  int node = stripe * NPS + (blockIdx.x >> 3) * 4 + (threadIdx.x >> 6);
  int lane = threadIdx.x & 63;
  int g = lane >> 3;
  int i = lane & 7;
  int c = cnt[node];
  int m = min(c, K);
  int sv = (lane < m) ? csr[node * K + lane] : node;   // coalesced 128B bucket read
  const uint4* H4 = (const uint4*)Hs2;
  float acc0 = 0, acc1 = 0, acc2 = 0, acc3 = 0, acc4 = 0, acc5 = 0, acc6 = 0, acc7 = 0;
  for (int k = 0; k < m; k += 8) {
    int j = k + g;
    int s = __shfl(sv, j);
    bool valid = j < m;
    uint4 h = H4[(valid ? s : node) * 8 + i];
    if (valid) {
      acc0 += __uint_as_float(h.x << 16); acc1 += __uint_as_float(h.x & 0xFFFF0000u);
      acc2 += __uint_as_float(h.y << 16); acc3 += __uint_as_float(h.y & 0xFFFF0000u);
      acc4 += __uint_as_float(h.z << 16); acc5 += __uint_as_float(h.z & 0xFFFF0000u);
      acc6 += __uint_as_float(h.w << 16); acc7 += __uint_as_float(h.w & 0xFFFF0000u);
    }
  }
  int on = min(*ovf_cnt, OVF_CAP);
  if (on > 0 && g == 0) {                  // exact rare path (deg > K)
    for (int j = 0; j < on; j++)
      if (ovf[2 * j + 1] == node) {
        uint4 h = H4[ovf[2 * j] * 8 + i];
        acc0 += __uint_as_float(h.x << 16); acc1 += __uint_as_float(h.x & 0xFFFF0000u);
        acc2 += __uint_as_float(h.y << 16); acc3 += __uint_as_float(h.y & 0xFFFF0000u);
        acc4 += __uint_as_float(h.z << 16); acc5 += __uint_as_float(h.z & 0xFFFF0000u);
        acc6 += __uint_as_float(h.w << 16); acc7 += __uint_as_float(h.w & 0xFFFF0000u);
      }
  }
#pragma unroll
  for (int off = 8; off < 64; off <<= 1) {
    acc0 += __shfl_xor(acc0, off); acc1 += __shfl_xor(acc1, off);
    acc2 += __shfl_xor(acc2, off); acc3 += __shfl_xor(acc3, off);
    acc4 += __shfl_xor(acc4, off); acc5 += __shfl_xor(acc5, off);
    acc6 += __shfl_xor(acc6, off); acc7 += __shfl_xor(acc7, off);
  }
  if (g == 0) {
    uint4 hs = H4[node * 8 + i];
    float di = rsqrtf((float)c + 1.0f);
    const float4* b4 = (const float4*)b;
    float4 blo = b4[2 * i], bhi = b4[2 * i + 1];
    float4 o0, o1;
    o0.x = fmaxf(di * (acc0 + __uint_as_float(hs.x << 16)) + blo.x, 0.f);
    o0.y = fmaxf(di * (acc1 + __uint_as_float(hs.x & 0xFFFF0000u)) + blo.y, 0.f);
    o0.z = fmaxf(di * (acc2 + __uint_as_float(hs.y << 16)) + blo.z, 0.f);
    o0.w = fmaxf(di * (acc3 + __uint_as_float(hs.y & 0xFFFF0000u)) + blo.w, 0.f);
    o1.x = fmaxf(di * (acc4 + __uint_as_float(hs.z << 16)) + bhi.x, 0.f);
    o1.y = fmaxf(di * (acc5 + __uint_as_float(hs.z & 0xFFFF0000u)) + bhi.y, 0.f);
    o1.z = fmaxf(di * (acc6 + __uint_as_float(hs.w << 16)) + bhi.z, 0.f);
    o1.w = fmaxf(di * (acc7 + __uint_as_float(hs.w & 0xFFFF0000u)) + bhi.w, 0.f);
    ((float4*)Xout)[node * 16 + 2 * i] = o0;
    ((float4*)Xout)[node * 16 + 2 * i + 1] = o1;
  }
}

// ---- pool + classifier -----------------------------------------------------
__global__ void pool_kernel(const float* __restrict__ X, const int* __restrict__ batch,
                            float* __restrict__ sums, float* __restrict__ cnts) {
  int lane = threadIdx.x & 63;
  int wid = (blockIdx.x * blockDim.x + threadIdx.x) >> 6;
  int nw = (gridDim.x * blockDim.x) >> 6;
  int per = (N + nw - 1) / nw;
  int start = wid * per;
  int end = min(start + per, N);
  float acc = 0.f, cnt = 0.f;
  int cur = -1;
  for (int n = start; n < end; n++) {
    int g = batch[n];
    if (g != cur) {
      if (cur >= 0) {
        atomicAdd(&sums[cur * 64 + lane], acc);
        if (lane == 0) atomicAdd(&cnts[cur], cnt);
      }
      cur = g; acc = 0.f; cnt = 0.f;
    }
    acc += X[n * 64 + lane];
    cnt += 1.f;
  }
  if (cur >= 0) {
    atomicAdd(&sums[cur * 64 + lane], acc);
    if (lane == 0) atomicAdd(&cnts[cur], cnt);
  }
}

__global__ void classifier_kernel(const float* __restrict__ sums, const float* __restrict__ cnts,
                                  const float* __restrict__ Wc1, const float* __restrict__ bc1,
                                  const float* __restrict__ Wc2, const float* __restrict__ bc2,
                                  float* __restrict__ out) {
  __shared__ float pooled[64 * 64];
  __shared__ float z[64 * 32];
  int tid = threadIdx.x;
  for (int idx = tid; idx < 64 * 64; idx += 256) {
    int g = idx >> 6;
    pooled[idx] = sums[idx] / fmaxf(cnts[g], 1.0f);
  }
  __syncthreads();
  for (int idx = tid; idx < 64 * 32; idx += 256) {
    int g = idx >> 5, j = idx & 31;
    float acc = bc1[j];
#pragma unroll
    for (int c = 0; c < 64; c++) acc += pooled[g * 64 + c] * Wc1[c * 32 + j];
    z[idx] = fmaxf(acc, 0.f);
  }
  __syncthreads();
  for (int idx = tid; idx < 128; idx += 256) {
    int g = idx >> 1, k = idx & 1;
    float acc = bc2[k];
#pragma unroll
    for (int j = 0; j < 32; j++) acc += z[g * 32 + j] * Wc2[j * 2 + k];
    out[idx] = acc;
  }
}

// ---- launch ----------------------------------------------------------------
extern "C" void kernel_launch(void* const* d_in, const int* in_sizes, int n_in,
                              void* d_out, int out_size, void* d_ws, size_t ws_size,
                              hipStream_t stream) {
  const float* x   = (const float*)d_in[0];
  const float* W1  = (const float*)d_in[1];
  const float* b1  = (const float*)d_in[2];
  const float* W2  = (const float*)d_in[3];
  const float* b2  = (const float*)d_in[4];
  const float* W3  = (const float*)d_in[5];
  const float* b3  = (const float*)d_in[6];
  const float* Wc1 = (const float*)d_in[7];
  const float* bc1 = (const float*)d_in[8];
  const float* Wc2 = (const float*)d_in[9];
  const float* bc2 = (const float*)d_in[10];
  const int* ei    = (const int*)d_in[11];
  const int* batch = (const int*)d_in[12];
  const int* src  = ei;
  const int* dstp = ei + E;

  char* ws = (char*)d_ws;
  size_t off = 0;
  auto alloc = [&](size_t bytes) {
    char* p = ws + off;
    off += (bytes + 255) & ~size_t(255);
    return p;
  };
  int*      cnt  = (int*)alloc((size_t)(N + 1) * 4);
  int*      csr  = (int*)alloc((size_t)N * K * 4);          // 12.8 MB
  int*      ovf  = (int*)alloc((size_t)OVF_CAP * 2 * 4);
  unsigned* Hs   = (unsigned*)alloc((size_t)N * 64 * 2);    // bf16
  float*    B1   = (float*)alloc((size_t)N * 64 * 4);
  float*    sums = (float*)alloc((size_t)(G * 64 + G) * 4);
  float*    cnts = sums + G * 64;
  int*      ovf_cnt = cnt + N;

  hipMemsetAsync(cnt, 0, (size_t)(N + 1) * 4, stream);
  hipMemsetAsync(sums, 0, (size_t)(G * 64 + G) * 4, stream);

  build_kernel<<<CPB * STRIPES, 256, 0, stream>>>(src, dstp, cnt, csr, ovf, ovf_cnt);

  const float* Xc = x;
  const float* Wl[3] = {W1, W2, W3};
  const float* bl[3] = {b1, b2, b3};
  for (int l = 0; l < 3; l++) {
    gemm_premul_kernel<<<N / 32, 256, 0, stream>>>(Xc, Wl[l], cnt, Hs);
    agg_kernel<<<(NPS / 4) * STRIPES, 256, 0, stream>>>(Hs, cnt, csr, ovf, ovf_cnt, bl[l], B1);
    Xc = B1;
  }

  pool_kernel<<<512, 256, 0, stream>>>(Xc, batch, sums, cnts);
  classifier_kernel<<<1, 256, 0, stream>>>(sums, cnts, Wc1, bc1, Wc2, bc2, (float*)d_out);
}